// Round 1
// baseline (851.578 us; speedup 1.0000x reference)
//
#include <hip/hip_runtime.h>
#include <stdint.h>

// CoAttention, MI355X. B=4, C=2048, H=W=48 (HW=2304), HC=256.
// Pipeline: convert+copy -> W split -> 4x proj (Wh/Wl x Xf16, transposed store)
//           -> per direction: scores (3-term split f16 MFMA) -> softmax (f32, in-place f16 attn)
//           -> PV (f16 MFMA NT GEMM) into d_out.
// Workspace: 203 MB.

#define NB 4
#define NC 2048
#define NHW 2304
#define NHC 256

typedef _Float16 f16;
typedef __attribute__((ext_vector_type(4))) _Float16 f16x4;
typedef __attribute__((ext_vector_type(8))) _Float16 f16x8;
typedef __attribute__((ext_vector_type(4))) float f32x4;

static __device__ __forceinline__ void glds16(const void* g, void* lds) {
  __builtin_amdgcn_global_load_lds(
      (const __attribute__((address_space(1))) uint32_t*)g,
      (__attribute__((address_space(3))) uint32_t*)lds, 16, 0, 0);
}

// ---------------- convert features to f16 + copy originals into output ----------------
__global__ __launch_bounds__(256) void k_convert_copy(
    const float* __restrict__ xl, const float* __restrict__ xr,
    float* __restrict__ out, f16* __restrict__ xh) {
  const int SIDE4 = NB * NC * NHW / 4;  // 4718592 float4s per side
  int idx = blockIdx.x * 256 + threadIdx.x;
  int side = (idx >= SIDE4) ? 1 : 0;
  int e4 = idx - side * SIDE4;
  const float* src = side ? xr : xl;
  float4 v = ((const float4*)src)[e4];
  f16x4 h;
  h[0] = (f16)v.x; h[1] = (f16)v.y; h[2] = (f16)v.z; h[3] = (f16)v.w;
  ((f16x4*)xh)[side * SIDE4 + e4] = h;
  int e = e4 * 4;
  int b = e / (NC * NHW);
  int r = e - b * (NC * NHW);
  size_t off = (size_t)side * (NB * 2 * NC * NHW) + (size_t)b * (2 * NC * NHW) + r;
  *(float4*)(out + off) = v;  // original features -> channels [0,2048) of concat
}

// ---------------- split Wq/Wk into f16 hi + lo ----------------
__global__ __launch_bounds__(256) void k_convert_w(
    const float* __restrict__ wq, const float* __restrict__ wk,
    f16* __restrict__ whq, f16* __restrict__ wlq,
    f16* __restrict__ whk, f16* __restrict__ wlk) {
  const int N4 = NHC * NC / 4;  // 131072
  int idx = blockIdx.x * 256 + threadIdx.x;
  const float* src; f16 *dh, *dl; int e4;
  if (idx < N4) { src = wq; dh = whq; dl = wlq; e4 = idx; }
  else          { src = wk; dh = whk; dl = wlk; e4 = idx - N4; }
  float4 v = ((const float4*)src)[e4];
  float a[4] = {v.x, v.y, v.z, v.w};
  f16x4 h, l;
#pragma unroll
  for (int c = 0; c < 4; ++c) {
    f16 hh = (f16)a[c];
    h[c] = hh;
    l[c] = (f16)(a[c] - (float)hh);
  }
  ((f16x4*)dh)[e4] = h;
  ((f16x4*)dl)[e4] = l;
}

// ---------------- projection: Yt[b][i][o] = sum_c W[o,c]*X[b,c,i] + bias[o] ----------------
// A = W (hi+lo, 2-term MFMA), B = X f32 staged->f16 transposed in LDS.
// BM=128, BN=64, BK=32. Output stored TRANSPOSED [i][o] as hi/lo f16 pairs.
__global__ __launch_bounds__(256) void k_proj(
    const float* __restrict__ X, const f16* __restrict__ Wh,
    const f16* __restrict__ Wl, const float* __restrict__ bias,
    f16* __restrict__ Yh, f16* __restrict__ Yl) {
  __shared__ f16 Ah[128 * 32];
  __shared__ f16 Al[128 * 32];
  __shared__ f16 Bx[64][40];  // [n][k], padded to 40 halves (80B) -> 2-way banks
  const int b = blockIdx.z;
  const int m0 = blockIdx.x * 128, n0 = blockIdx.y * 64;
  const int tid = threadIdx.x, wv = tid >> 6, ln = tid & 63;
  const int lr = ln & 15, lh = ln >> 4;
  const int wm = wv >> 1, wn = wv & 1;
  const float* Xb = X + (size_t)b * NC * NHW;
  f32x4 acc[4][2];
#pragma unroll
  for (int mi = 0; mi < 4; ++mi)
#pragma unroll
    for (int ni = 0; ni < 2; ++ni)
#pragma unroll
      for (int q = 0; q < 4; ++q) acc[mi][ni][q] = 0.f;

  for (int ks = 0; ks < NC / 32; ++ks) {
    int k0 = ks * 32;
#pragma unroll
    for (int rep = 0; rep < 2; ++rep) {
      int u = rep * 256 + wv * 64 + ln;
      int m = u >> 2, k8 = (u & 3) * 8;
      int ub = rep * 256 + wv * 64;  // wave-uniform chunk base
      glds16(Wh + (size_t)(m0 + m) * NC + k0 + k8, Ah + ub * 8);
      glds16(Wl + (size_t)(m0 + m) * NC + k0 + k8, Al + ub * 8);
    }
#pragma unroll
    for (int rep = 0; rep < 8; ++rep) {
      int idx = rep * 256 + tid;
      int n = idx & 63, k = idx >> 6;
      Bx[n][k] = (f16)Xb[(size_t)(k0 + k) * NHW + n0 + n];
    }
    __syncthreads();
    f16x8 ah[4], al[4], bf[2];
#pragma unroll
    for (int mi = 0; mi < 4; ++mi) {
      int row = wm * 64 + mi * 16 + lr;
      ah[mi] = *(const f16x8*)&Ah[row * 32 + lh * 8];
      al[mi] = *(const f16x8*)&Al[row * 32 + lh * 8];
    }
#pragma unroll
    for (int ni = 0; ni < 2; ++ni) {
      int col = wn * 32 + ni * 16 + lr;
      bf[ni] = *(const f16x8*)&Bx[col][lh * 8];
    }
#pragma unroll
    for (int mi = 0; mi < 4; ++mi)
#pragma unroll
      for (int ni = 0; ni < 2; ++ni) {
        acc[mi][ni] = __builtin_amdgcn_mfma_f32_16x16x32_f16(ah[mi], bf[ni], acc[mi][ni], 0, 0, 0);
        acc[mi][ni] = __builtin_amdgcn_mfma_f32_16x16x32_f16(al[mi], bf[ni], acc[mi][ni], 0, 0, 0);
      }
    __syncthreads();
  }
  f16* Yhb = Yh + (size_t)b * NHW * NHC;
  f16* Ylb = Yl + (size_t)b * NHW * NHC;
#pragma unroll
  for (int mi = 0; mi < 4; ++mi)
#pragma unroll
    for (int ni = 0; ni < 2; ++ni) {
      int i  = n0 + wn * 32 + ni * 16 + lr;        // D col -> pixel
      int ob = m0 + wm * 64 + mi * 16 + lh * 4;    // D row base -> out channel
      f16x4 hv, lv;
#pragma unroll
      for (int q = 0; q < 4; ++q) {
        float vv = acc[mi][ni][q] + bias[ob + q];
        f16 hh = (f16)vv;
        hv[q] = hh;
        lv[q] = (f16)(vv - (float)hh);
      }
      *(f16x4*)&Yhb[(size_t)i * NHC + ob] = hv;
      *(f16x4*)&Ylb[(size_t)i * NHC + ob] = lv;
    }
}

// ---------------- scores: S[b][i][j] = sum_hc Qt[i,hc]*Kt[j,hc], 3-term split ----------------
// BM=BN=128, BK=32, K=256. Pure NT GEMM, all operands K-contiguous.
__global__ __launch_bounds__(256) void k_scores(
    const f16* __restrict__ Qh, const f16* __restrict__ Ql,
    const f16* __restrict__ Kh, const f16* __restrict__ Kl,
    float* __restrict__ S) {
  __shared__ f16 LQh[128 * 32], LQl[128 * 32], LKh[128 * 32], LKl[128 * 32];
  const int b = blockIdx.z;
  const int i0 = blockIdx.x * 128, j0 = blockIdx.y * 128;
  const int tid = threadIdx.x, wv = tid >> 6, ln = tid & 63;
  const int lr = ln & 15, lh = ln >> 4;
  const int wm = wv >> 1, wn = wv & 1;
  const size_t bo = (size_t)b * NHW * NHC;
  const f16* Qhb = Qh + bo; const f16* Qlb = Ql + bo;
  const f16* Khb = Kh + bo; const f16* Klb = Kl + bo;
  f32x4 acc[4][4];
#pragma unroll
  for (int mi = 0; mi < 4; ++mi)
#pragma unroll
    for (int ni = 0; ni < 4; ++ni)
#pragma unroll
      for (int q = 0; q < 4; ++q) acc[mi][ni][q] = 0.f;

  for (int ks = 0; ks < NHC / 32; ++ks) {
    int k0 = ks * 32;
#pragma unroll
    for (int rep = 0; rep < 2; ++rep) {
      int u = rep * 256 + wv * 64 + ln;
      int r = u >> 2, k8 = (u & 3) * 8;
      int ub8 = (rep * 256 + wv * 64) * 8;
      glds16(Qhb + (size_t)(i0 + r) * NHC + k0 + k8, LQh + ub8);
      glds16(Qlb + (size_t)(i0 + r) * NHC + k0 + k8, LQl + ub8);
      glds16(Khb + (size_t)(j0 + r) * NHC + k0 + k8, LKh + ub8);
      glds16(Klb + (size_t)(j0 + r) * NHC + k0 + k8, LKl + ub8);
    }
    __syncthreads();
    f16x8 qh[4], ql[4], kh[4], kl[4];
#pragma unroll
    for (int mi = 0; mi < 4; ++mi) {
      int row = wm * 64 + mi * 16 + lr;
      qh[mi] = *(const f16x8*)&LQh[row * 32 + lh * 8];
      ql[mi] = *(const f16x8*)&LQl[row * 32 + lh * 8];
    }
#pragma unroll
    for (int ni = 0; ni < 4; ++ni) {
      int row = wn * 64 + ni * 16 + lr;
      kh[ni] = *(const f16x8*)&LKh[row * 32 + lh * 8];
      kl[ni] = *(const f16x8*)&LKl[row * 32 + lh * 8];
    }
#pragma unroll
    for (int mi = 0; mi < 4; ++mi)
#pragma unroll
      for (int ni = 0; ni < 4; ++ni) {
        acc[mi][ni] = __builtin_amdgcn_mfma_f32_16x16x32_f16(qh[mi], kh[ni], acc[mi][ni], 0, 0, 0);
        acc[mi][ni] = __builtin_amdgcn_mfma_f32_16x16x32_f16(qh[mi], kl[ni], acc[mi][ni], 0, 0, 0);
        acc[mi][ni] = __builtin_amdgcn_mfma_f32_16x16x32_f16(ql[mi], kh[ni], acc[mi][ni], 0, 0, 0);
      }
    __syncthreads();
  }
  float* Sb = S + (size_t)b * NHW * NHW;
#pragma unroll
  for (int mi = 0; mi < 4; ++mi)
#pragma unroll
    for (int ni = 0; ni < 4; ++ni) {
      int i = i0 + wm * 64 + mi * 16 + lh * 4;
      int j = j0 + wn * 64 + ni * 16 + lr;
#pragma unroll
      for (int q = 0; q < 4; ++q)
        Sb[(size_t)(i + q) * NHW + j] = acc[mi][ni][q];
    }
}

// ---------------- row softmax, f32 -> f16 attn written in-place over row start ----------------
__global__ __launch_bounds__(256) void k_softmax(float* __restrict__ S) {
  const int row = blockIdx.x;  // 0 .. NB*NHW-1
  float* rp = S + (size_t)row * NHW;
  const int t = threadIdx.x;
  float v[9];
  float m = -3.4e38f;
#pragma unroll
  for (int k = 0; k < 9; ++k) { v[k] = rp[t + 256 * k]; m = fmaxf(m, v[k]); }
#pragma unroll
  for (int off = 32; off > 0; off >>= 1) m = fmaxf(m, __shfl_xor(m, off));
  __shared__ float red[4];
  __shared__ float red2[4];
  const int wv = t >> 6, ln = t & 63;
  if (ln == 0) red[wv] = m;
  __syncthreads();
  m = fmaxf(fmaxf(red[0], red[1]), fmaxf(red[2], red[3]));
  float s = 0.f;
#pragma unroll
  for (int k = 0; k < 9; ++k) { v[k] = expf(v[k] - m); s += v[k]; }
#pragma unroll
  for (int off = 32; off > 0; off >>= 1) s += __shfl_xor(s, off);
  if (ln == 0) red2[wv] = s;
  __syncthreads();
  float inv = 1.0f / (red2[0] + red2[1] + red2[2] + red2[3]);
  f16* op = (f16*)rp;  // in-place: all reads completed before first barrier
#pragma unroll
  for (int k = 0; k < 9; ++k) op[t + 256 * k] = (f16)(v[k] * inv);
}

// ---------------- PV: out[b][2048+c][i] = sum_j V[b][c][j] * attn[b][i][j] ----------------
// A = V f16 [C][HW] (K-contig), B = attn f16 rows embedded in S (row stride 9216 B).
__global__ __launch_bounds__(256) void k_pv(
    const f16* __restrict__ V, const float* __restrict__ S,
    float* __restrict__ out, int obase) {
  __shared__ f16 LA[128 * 32], LB[128 * 32];
  const int b = blockIdx.z;
  const int c0 = blockIdx.x * 128, i0 = blockIdx.y * 128;
  const int tid = threadIdx.x, wv = tid >> 6, ln = tid & 63;
  const int lr = ln & 15, lh = ln >> 4;
  const int wm = wv >> 1, wn = wv & 1;
  const f16* Vb = V + (size_t)b * NC * NHW;
  const char* Sb = (const char*)S + (size_t)b * NHW * NHW * 4;
  f32x4 acc[4][4];
#pragma unroll
  for (int mi = 0; mi < 4; ++mi)
#pragma unroll
    for (int ni = 0; ni < 4; ++ni)
#pragma unroll
      for (int q = 0; q < 4; ++q) acc[mi][ni][q] = 0.f;

  for (int ks = 0; ks < NHW / 32; ++ks) {
    int k0 = ks * 32;
#pragma unroll
    for (int rep = 0; rep < 2; ++rep) {
      int u = rep * 256 + wv * 64 + ln;
      int r = u >> 2, k8 = (u & 3) * 8;
      int ub8 = (rep * 256 + wv * 64) * 8;
      glds16(Vb + (size_t)(c0 + r) * NHW + k0 + k8, LA + ub8);
      glds16((const f16*)(Sb + (size_t)(i0 + r) * 9216) + k0 + k8, LB + ub8);
    }
    __syncthreads();
    f16x8 af[4], bf[4];
#pragma unroll
    for (int mi = 0; mi < 4; ++mi) {
      int row = wm * 64 + mi * 16 + lr;
      af[mi] = *(const f16x8*)&LA[row * 32 + lh * 8];
    }
#pragma unroll
    for (int ni = 0; ni < 4; ++ni) {
      int row = wn * 64 + ni * 16 + lr;
      bf[ni] = *(const f16x8*)&LB[row * 32 + lh * 8];
    }
#pragma unroll
    for (int mi = 0; mi < 4; ++mi)
#pragma unroll
      for (int ni = 0; ni < 4; ++ni)
        acc[mi][ni] = __builtin_amdgcn_mfma_f32_16x16x32_f16(af[mi], bf[ni], acc[mi][ni], 0, 0, 0);
    __syncthreads();
  }
  float* ob = out + (size_t)obase + (size_t)b * (2 * NC * NHW);
#pragma unroll
  for (int mi = 0; mi < 4; ++mi)
#pragma unroll
    for (int ni = 0; ni < 4; ++ni) {
      int c = c0 + wm * 64 + mi * 16 + lh * 4;
      int i = i0 + wn * 64 + ni * 16 + lr;
#pragma unroll
      for (int q = 0; q < 4; ++q)
        ob[(size_t)(NC + c + q) * NHW + i] = acc[mi][ni][q];
    }
}

extern "C" void kernel_launch(void* const* d_in, const int* in_sizes, int n_in,
                              void* d_out, int out_size, void* d_ws, size_t ws_size,
                              hipStream_t stream) {
  const float* xl = (const float*)d_in[0];
  const float* xr = (const float*)d_in[1];
  const float* wq = (const float*)d_in[2];
  const float* bq = (const float*)d_in[3];
  const float* wk = (const float*)d_in[4];
  const float* bk = (const float*)d_in[5];
  float* out = (float*)d_out;
  char* ws = (char*)d_ws;

  const size_t SX = (size_t)NB * NC * NHW * 2;   // 37,748,736 B (f16 features per side)
  const size_t SW = (size_t)NHC * NC * 2;        // 1,048,576 B
  const size_t SQ = (size_t)NB * NHW * NHC * 2;  // 4,718,592 B
  // total ws use: 2*SX + 4*SW + 8*SQ + NB*NHW*NHW*4 = 202,375,168 B

  f16* Xh  = (f16*)ws;                    // [2][NB][NC][NHW], left then right
  f16* WhQ = (f16*)(ws + 2 * SX);
  f16* WlQ = (f16*)(ws + 2 * SX + SW);
  f16* WhK = (f16*)(ws + 2 * SX + 2 * SW);
  f16* WlK = (f16*)(ws + 2 * SX + 3 * SW);
  char* qb = ws + 2 * SX + 4 * SW;
  f16* QtAh = (f16*)(qb);
  f16* QtAl = (f16*)(qb + SQ);
  f16* KtAh = (f16*)(qb + 2 * SQ);
  f16* KtAl = (f16*)(qb + 3 * SQ);
  f16* QtBh = (f16*)(qb + 4 * SQ);
  f16* QtBl = (f16*)(qb + 5 * SQ);
  f16* KtBh = (f16*)(qb + 6 * SQ);
  f16* KtBl = (f16*)(qb + 7 * SQ);
  float* S  = (float*)(qb + 8 * SQ);      // [NB][NHW][NHW] f32, reused for both directions

  k_convert_copy<<<dim3(36864), dim3(256), 0, stream>>>(xl, xr, out, Xh);
  k_convert_w<<<dim3(1024), dim3(256), 0, stream>>>(wq, wk, WhQ, WlQ, WhK, WlK);

  dim3 gp(2, 36, NB);
  k_proj<<<gp, dim3(256), 0, stream>>>(xl, WhQ, WlQ, bq, QtAh, QtAl);  // Q from left
  k_proj<<<gp, dim3(256), 0, stream>>>(xr, WhK, WlK, bk, KtAh, KtAl);  // K from right
  k_proj<<<gp, dim3(256), 0, stream>>>(xr, WhQ, WlQ, bq, QtBh, QtBl);  // Q from right
  k_proj<<<gp, dim3(256), 0, stream>>>(xl, WhK, WlK, bk, KtBh, KtBl);  // K from left

  dim3 gs(18, 18, NB);
  dim3 gv(16, 18, NB);
  // direction A: Q(left)·K(right), V = right  -> right_attended weighted half
  k_scores<<<gs, dim3(256), 0, stream>>>(QtAh, QtAl, KtAh, KtAl, S);
  k_softmax<<<dim3(NB * NHW), dim3(256), 0, stream>>>(S);
  k_pv<<<gv, dim3(256), 0, stream>>>(Xh + (size_t)NB * NC * NHW, S, out, NB * 2 * NC * NHW);
  // direction B: Q(right)·K(left), V = left   -> left_attended weighted half
  k_scores<<<gs, dim3(256), 0, stream>>>(QtBh, QtBl, KtBh, KtBl, S);
  k_softmax<<<dim3(NB * NHW), dim3(256), 0, stream>>>(S);
  k_pv<<<gv, dim3(256), 0, stream>>>(Xh, S, out, 0);
}

// Round 2
// 576.274 us; speedup vs baseline: 1.4777x; 1.4777x over previous
//
#include <hip/hip_runtime.h>
#include <stdint.h>

// CoAttention, MI355X. B=4, C=2048, H=W=48 (HW=2304), HC=256.
// r2: all-f16 single-term MFMA (error budget allows), fused Q|K proj reading
// pre-transposed Xt via global_load_lds, 2-phase double-buffered pipelines.

#define NB 4
#define NC 2048
#define NHW 2304
#define NHC 256

typedef _Float16 f16;
typedef __attribute__((ext_vector_type(4))) _Float16 f16x4;
typedef __attribute__((ext_vector_type(8))) _Float16 f16x8;
typedef __attribute__((ext_vector_type(4))) float f32x4;

static __device__ __forceinline__ void glds16(const void* g, void* lds) {
  __builtin_amdgcn_global_load_lds(
      (const __attribute__((address_space(1))) uint32_t*)g,
      (__attribute__((address_space(3))) uint32_t*)lds, 16, 0, 0);
}

// ---- prep: copy originals to out, X->f16 (Xh, [c][hw]) and X^T->f16 (Xt, [hw][c]) ----
// grid (36 hw-tiles, 32 c-tiles, 8 = side*4+b), 64x64 tiles.
__global__ __launch_bounds__(256) void k_prep(
    const float* __restrict__ xl, const float* __restrict__ xr,
    float* __restrict__ out, f16* __restrict__ Xh, f16* __restrict__ Xt) {
  const int z = blockIdx.z, side = z >> 2, b = z & 3;
  const float* X = (side ? xr : xl) + (size_t)b * NC * NHW;
  const int hw0 = blockIdx.x * 64, c0 = blockIdx.y * 64;
  const int t = threadIdx.x;
  const int colb = (t & 15) * 4;  // hw offset within tile
  const int r0 = t >> 4;          // c row base
  __shared__ f16 Lt[64 * 64];     // [hw][c], 16B-chunk XOR swizzle on (row>>2)&7
  float* outb = out + (size_t)side * ((size_t)NB * 2 * NC * NHW) + (size_t)b * (2 * NC * NHW);
  f16* Xhb = Xh + (size_t)side * ((size_t)NB * NC * NHW) + (size_t)b * NC * NHW;
  f16* Xtb = Xt + (size_t)side * ((size_t)NB * NHW * NC) + (size_t)b * NHW * NC;
#pragma unroll
  for (int p = 0; p < 4; ++p) {
    int r = r0 + p * 16;
    size_t go = (size_t)(c0 + r) * NHW + hw0 + colb;
    float4 v = *(const float4*)&X[go];
    *(float4*)&outb[go] = v;
    f16x4 h; h[0] = (f16)v.x; h[1] = (f16)v.y; h[2] = (f16)v.z; h[3] = (f16)v.w;
    *(f16x4*)&Xhb[go] = h;
#pragma unroll
    for (int j = 0; j < 4; ++j) {
      int row = colb + j;  // hw_local
      int byte = row * 128 + ((r * 2) ^ ((((row >> 2) & 7)) << 4));
      *(f16*)((char*)Lt + byte) = h[j];
    }
  }
  __syncthreads();
#pragma unroll
  for (int p = 0; p < 2; ++p) {
    int idx = p * 256 + t;
    int row = idx >> 3, ch = idx & 7;
    int byte = row * 128 + (((ch ^ ((row >> 2) & 7))) << 4);
    f16x8 vv = *(const f16x8*)((char*)Lt + byte);
    *(f16x8*)&Xtb[(size_t)(hw0 + row) * NC + c0 + ch * 8] = vv;
  }
}

// ---- W stack to f16: Ws[512][2048], rows 0-255 = Wq, 256-511 = Wk ----
__global__ __launch_bounds__(256) void k_w16(
    const float* __restrict__ wq, const float* __restrict__ wk, f16* __restrict__ Ws) {
  const int N4 = NHC * NC / 4;  // 131072
  int idx = blockIdx.x * 256 + threadIdx.x;
  const float* src = (idx < N4) ? wq : wk;
  int e4 = (idx < N4) ? idx : idx - N4;
  float4 v = ((const float4*)src)[e4];
  f16x4 h; h[0] = (f16)v.x; h[1] = (f16)v.y; h[2] = (f16)v.z; h[3] = (f16)v.w;
  ((f16x4*)Ws)[idx] = h;
}

// ---- proj: D[o][i] = sum_c Ws[o][c]*Xt[i][c]; write Yt[i][512] f16 (+bias) ----
// grid (72 n-tiles over NB*NHW, 4 m-tiles), 128x128, BK=32, 2-phase dbuf.
__global__ __launch_bounds__(256) void k_proj(
    const f16* __restrict__ Ws, const f16* __restrict__ Xt,
    const float* __restrict__ bq, const float* __restrict__ bk,
    f16* __restrict__ Yt) {
  __shared__ f16 LA[2][128 * 32], LB[2][128 * 32];
  const int n0 = blockIdx.x * 128;  // combined pixel row (b*NHW+hw)
  const int m0 = blockIdx.y * 128;  // out channel
  const int tid = threadIdx.x, wv = tid >> 6, ln = tid & 63;
  const int lr = ln & 15, lh = ln >> 4;
  const int wm = wv >> 1, wn = wv & 1;
  f32x4 acc[4][4];
#pragma unroll
  for (int mi = 0; mi < 4; ++mi)
#pragma unroll
    for (int ni = 0; ni < 4; ++ni)
#pragma unroll
      for (int q = 0; q < 4; ++q) acc[mi][ni][q] = 0.f;

  auto stage = [&](int bi, int ks) {
    int k0 = ks * 32;
#pragma unroll
    for (int rep = 0; rep < 2; ++rep) {
      int u = rep * 256 + wv * 64 + ln;
      int r = u >> 2, k8 = (u & 3) * 8;
      int ub8 = (rep * 256 + wv * 64) * 8;
      glds16(Ws + (size_t)(m0 + r) * NC + k0 + k8, &LA[bi][ub8]);
      glds16(Xt + (size_t)(n0 + r) * NC + k0 + k8, &LB[bi][ub8]);
    }
  };
  auto compute = [&](int bi) {
    f16x8 af[4], bf[4];
#pragma unroll
    for (int mi = 0; mi < 4; ++mi)
      af[mi] = *(const f16x8*)&LA[bi][(wm * 64 + mi * 16 + lr) * 32 + lh * 8];
#pragma unroll
    for (int ni = 0; ni < 4; ++ni)
      bf[ni] = *(const f16x8*)&LB[bi][(wn * 64 + ni * 16 + lr) * 32 + lh * 8];
#pragma unroll
    for (int mi = 0; mi < 4; ++mi)
#pragma unroll
      for (int ni = 0; ni < 4; ++ni)
        acc[mi][ni] = __builtin_amdgcn_mfma_f32_16x16x32_f16(af[mi], bf[ni], acc[mi][ni], 0, 0, 0);
  };

  stage(0, 0);
  __syncthreads();
  int cur = 0;
  for (int ks = 0; ks < 63; ++ks) {
    stage(cur ^ 1, ks + 1);
    compute(cur);
    __syncthreads();
    cur ^= 1;
  }
  compute(cur);

#pragma unroll
  for (int mi = 0; mi < 4; ++mi)
#pragma unroll
    for (int ni = 0; ni < 4; ++ni) {
      int ob = m0 + wm * 64 + mi * 16 + lh * 4;
      int i = n0 + wn * 64 + ni * 16 + lr;
      f16x4 hv;
#pragma unroll
      for (int q = 0; q < 4; ++q) {
        int o = ob + q;
        float bias = (o < NHC) ? bq[o] : bk[o - NHC];
        hv[q] = (f16)(acc[mi][ni][q] + bias);
      }
      *(f16x4*)&Yt[(size_t)i * 512 + ob] = hv;
    }
}

// ---- scores: S[b][i][j] = sum_hc Q[i,hc]*K[j,hc], rows stride 512 f16 ----
// grid (18, 18, NB), 128x128, BK=32, K=256 (8 steps), 2-phase dbuf.
__global__ __launch_bounds__(256) void k_scores(
    const f16* __restrict__ Q, const f16* __restrict__ K, float* __restrict__ S) {
  __shared__ f16 LA[2][128 * 32], LB[2][128 * 32];
  const int b = blockIdx.z;
  const int i0 = blockIdx.x * 128, j0 = blockIdx.y * 128;
  const int tid = threadIdx.x, wv = tid >> 6, ln = tid & 63;
  const int lr = ln & 15, lh = ln >> 4;
  const int wm = wv >> 1, wn = wv & 1;
  const f16* Qb = Q + (size_t)b * NHW * 512;
  const f16* Kb = K + (size_t)b * NHW * 512;
  f32x4 acc[4][4];
#pragma unroll
  for (int mi = 0; mi < 4; ++mi)
#pragma unroll
    for (int ni = 0; ni < 4; ++ni)
#pragma unroll
      for (int q = 0; q < 4; ++q) acc[mi][ni][q] = 0.f;

  auto stage = [&](int bi, int ks) {
    int k0 = ks * 32;
#pragma unroll
    for (int rep = 0; rep < 2; ++rep) {
      int u = rep * 256 + wv * 64 + ln;
      int r = u >> 2, k8 = (u & 3) * 8;
      int ub8 = (rep * 256 + wv * 64) * 8;
      glds16(Qb + (size_t)(i0 + r) * 512 + k0 + k8, &LA[bi][ub8]);
      glds16(Kb + (size_t)(j0 + r) * 512 + k0 + k8, &LB[bi][ub8]);
    }
  };
  auto compute = [&](int bi) {
    f16x8 af[4], bf[4];
#pragma unroll
    for (int mi = 0; mi < 4; ++mi)
      af[mi] = *(const f16x8*)&LA[bi][(wm * 64 + mi * 16 + lr) * 32 + lh * 8];
#pragma unroll
    for (int ni = 0; ni < 4; ++ni)
      bf[ni] = *(const f16x8*)&LB[bi][(wn * 64 + ni * 16 + lr) * 32 + lh * 8];
#pragma unroll
    for (int mi = 0; mi < 4; ++mi)
#pragma unroll
      for (int ni = 0; ni < 4; ++ni)
        acc[mi][ni] = __builtin_amdgcn_mfma_f32_16x16x32_f16(af[mi], bf[ni], acc[mi][ni], 0, 0, 0);
  };

  stage(0, 0);
  __syncthreads();
  int cur = 0;
  for (int ks = 0; ks < 7; ++ks) {
    stage(cur ^ 1, ks + 1);
    compute(cur);
    __syncthreads();
    cur ^= 1;
  }
  compute(cur);

  float* Sb = S + (size_t)b * NHW * NHW;
#pragma unroll
  for (int mi = 0; mi < 4; ++mi)
#pragma unroll
    for (int ni = 0; ni < 4; ++ni) {
      int i = i0 + wm * 64 + mi * 16 + lh * 4;
      int j = j0 + wn * 64 + ni * 16 + lr;
#pragma unroll
      for (int q = 0; q < 4; ++q)
        Sb[(size_t)(i + q) * NHW + j] = acc[mi][ni][q];
    }
}

// ---- row softmax, f32 -> f16 attn written in-place over row start ----
__global__ __launch_bounds__(256) void k_softmax(float* __restrict__ S) {
  const int row = blockIdx.x;
  float* rp = S + (size_t)row * NHW;
  const int t = threadIdx.x;
  float v[9];
  float m = -3.4e38f;
#pragma unroll
  for (int k = 0; k < 9; ++k) { v[k] = rp[t + 256 * k]; m = fmaxf(m, v[k]); }
#pragma unroll
  for (int off = 32; off > 0; off >>= 1) m = fmaxf(m, __shfl_xor(m, off));
  __shared__ float red[4];
  __shared__ float red2[4];
  const int wv = t >> 6, ln = t & 63;
  if (ln == 0) red[wv] = m;
  __syncthreads();
  m = fmaxf(fmaxf(red[0], red[1]), fmaxf(red[2], red[3]));
  float s = 0.f;
#pragma unroll
  for (int k = 0; k < 9; ++k) { v[k] = expf(v[k] - m); s += v[k]; }
#pragma unroll
  for (int off = 32; off > 0; off >>= 1) s += __shfl_xor(s, off);
  if (ln == 0) red2[wv] = s;
  __syncthreads();
  float inv = 1.0f / (red2[0] + red2[1] + red2[2] + red2[3]);
  f16* op = (f16*)rp;
#pragma unroll
  for (int k = 0; k < 9; ++k) op[t + 256 * k] = (f16)(v[k] * inv);
}

// ---- PV: out[b][2048+c][i] = sum_j V[b][c][j] * attn[b][i][j] ----
// grid (16, 18, NB), 128x128, BK=32, K=2304 (72 steps), 2-phase dbuf.
__global__ __launch_bounds__(256) void k_pv(
    const f16* __restrict__ V, const float* __restrict__ S,
    float* __restrict__ out, int obase) {
  __shared__ f16 LA[2][128 * 32], LB[2][128 * 32];
  const int b = blockIdx.z;
  const int c0 = blockIdx.x * 128, i0 = blockIdx.y * 128;
  const int tid = threadIdx.x, wv = tid >> 6, ln = tid & 63;
  const int lr = ln & 15, lh = ln >> 4;
  const int wm = wv >> 1, wn = wv & 1;
  const f16* Vb = V + (size_t)b * NC * NHW;
  const char* Sb = (const char*)S + (size_t)b * NHW * NHW * 4;
  f32x4 acc[4][4];
#pragma unroll
  for (int mi = 0; mi < 4; ++mi)
#pragma unroll
    for (int ni = 0; ni < 4; ++ni)
#pragma unroll
      for (int q = 0; q < 4; ++q) acc[mi][ni][q] = 0.f;

  auto stage = [&](int bi, int ks) {
    int k0 = ks * 32;
#pragma unroll
    for (int rep = 0; rep < 2; ++rep) {
      int u = rep * 256 + wv * 64 + ln;
      int r = u >> 2, k8 = (u & 3) * 8;
      int ub8 = (rep * 256 + wv * 64) * 8;
      glds16(Vb + (size_t)(c0 + r) * NHW + k0 + k8, &LA[bi][ub8]);
      glds16((const f16*)(Sb + (size_t)(i0 + r) * 9216) + k0 + k8, &LB[bi][ub8]);
    }
  };
  auto compute = [&](int bi) {
    f16x8 af[4], bf[4];
#pragma unroll
    for (int mi = 0; mi < 4; ++mi)
      af[mi] = *(const f16x8*)&LA[bi][(wm * 64 + mi * 16 + lr) * 32 + lh * 8];
#pragma unroll
    for (int ni = 0; ni < 4; ++ni)
      bf[ni] = *(const f16x8*)&LB[bi][(wn * 64 + ni * 16 + lr) * 32 + lh * 8];
#pragma unroll
    for (int mi = 0; mi < 4; ++mi)
#pragma unroll
      for (int ni = 0; ni < 4; ++ni)
        acc[mi][ni] = __builtin_amdgcn_mfma_f32_16x16x32_f16(af[mi], bf[ni], acc[mi][ni], 0, 0, 0);
  };

  stage(0, 0);
  __syncthreads();
  int cur = 0;
  for (int ks = 0; ks < 71; ++ks) {
    stage(cur ^ 1, ks + 1);
    compute(cur);
    __syncthreads();
    cur ^= 1;
  }
  compute(cur);

  float* ob = out + (size_t)obase + (size_t)b * (2 * NC * NHW);
#pragma unroll
  for (int mi = 0; mi < 4; ++mi)
#pragma unroll
    for (int ni = 0; ni < 4; ++ni) {
      int c = c0 + wm * 64 + mi * 16 + lh * 4;
      int i = i0 + wn * 64 + ni * 16 + lr;
#pragma unroll
      for (int q = 0; q < 4; ++q)
        ob[(size_t)(NC + c + q) * NHW + i] = acc[mi][ni][q];
    }
}

extern "C" void kernel_launch(void* const* d_in, const int* in_sizes, int n_in,
                              void* d_out, int out_size, void* d_ws, size_t ws_size,
                              hipStream_t stream) {
  const float* xl = (const float*)d_in[0];
  const float* xr = (const float*)d_in[1];
  const float* wq = (const float*)d_in[2];
  const float* bq = (const float*)d_in[3];
  const float* wk = (const float*)d_in[4];
  const float* bk = (const float*)d_in[5];
  float* out = (float*)d_out;
  char* ws = (char*)d_ws;

  const size_t XH_BYTES = (size_t)2 * NB * NC * NHW * 2;   // 75,497,472
  const size_t WS_BYTES = (size_t)512 * NC * 2;            //  2,097,152
  const size_t YT_BYTES = (size_t)2 * NB * NHW * 512 * 2;  // 18,874,368
  // S region: NB*NHW*NHW*4 = 84,934,656 ; Xt (75,497,472) aliases it.
  f16* Xh = (f16*)ws;
  f16* Ws_ = (f16*)(ws + XH_BYTES);
  f16* Yt = (f16*)(ws + XH_BYTES + WS_BYTES);
  char* srgn = ws + XH_BYTES + WS_BYTES + YT_BYTES;
  f16* Xt = (f16*)srgn;
  float* S = (float*)srgn;

  const size_t xh_side = (size_t)NB * NC * NHW;   // f16 elems per side
  const size_t xt_side = (size_t)NB * NHW * NC;
  const size_t yt_side = (size_t)NB * NHW * 512;

  k_prep<<<dim3(36, 32, 8), dim3(256), 0, stream>>>(xl, xr, out, Xh, Xt);
  k_w16<<<dim3(1024), dim3(256), 0, stream>>>(wq, wk, Ws_);

  k_proj<<<dim3(72, 4), dim3(256), 0, stream>>>(Ws_, Xt, bq, bk, Yt);                       // left
  k_proj<<<dim3(72, 4), dim3(256), 0, stream>>>(Ws_, Xt + xt_side, bq, bk, Yt + yt_side);   // right

  // direction A: Q(left)·K(right), V = right -> right_attended weighted half
  k_scores<<<dim3(18, 18, NB), dim3(256), 0, stream>>>(Yt, Yt + yt_side + NHC, S);
  k_softmax<<<dim3(NB * NHW), dim3(256), 0, stream>>>(S);
  k_pv<<<dim3(16, 18, NB), dim3(256), 0, stream>>>(Xh + xh_side, S, out, NB * 2 * NC * NHW);
  // direction B: Q(right)·K(left), V = left -> left_attended weighted half
  k_scores<<<dim3(18, 18, NB), dim3(256), 0, stream>>>(Yt + yt_side, Yt + NHC, S);
  k_softmax<<<dim3(NB * NHW), dim3(256), 0, stream>>>(S);
  k_pv<<<dim3(16, 18, NB), dim3(256), 0, stream>>>(Xh, S, out, 0);
}

// Round 3
// 504.840 us; speedup vs baseline: 1.6868x; 1.1415x over previous
//
#include <hip/hip_runtime.h>
#include <stdint.h>

// CoAttention, MI355X. B=4, C=2048, H=W=48 (HW=2304), HC=256.
// r3: PV rewritten as 256x128 ring-3 deep-pipelined MFMA kernel (counted vmcnt,
// raw s_barrier, LDS XOR swizzle, setprio), both directions merged into one
// dispatch when ws_size allows two score buffers.

#define NB 4
#define NC 2048
#define NHW 2304
#define NHC 256
#define NT 36  // K tiles of 64 over NHW

typedef _Float16 f16;
typedef __attribute__((ext_vector_type(4))) _Float16 f16x4;
typedef __attribute__((ext_vector_type(8))) _Float16 f16x8;
typedef __attribute__((ext_vector_type(4))) float f32x4;

static __device__ __forceinline__ void glds16(const void* g, void* lds) {
  __builtin_amdgcn_global_load_lds(
      (const __attribute__((address_space(1))) uint32_t*)g,
      (__attribute__((address_space(3))) uint32_t*)lds, 16, 0, 0);
}

// ---- prep: copy originals to out, X->f16 (Xh, [c][hw]) and X^T->f16 (Xt, [hw][c]) ----
__global__ __launch_bounds__(256) void k_prep(
    const float* __restrict__ xl, const float* __restrict__ xr,
    float* __restrict__ out, f16* __restrict__ Xh, f16* __restrict__ Xt) {
  const int z = blockIdx.z, side = z >> 2, b = z & 3;
  const float* X = (side ? xr : xl) + (size_t)b * NC * NHW;
  const int hw0 = blockIdx.x * 64, c0 = blockIdx.y * 64;
  const int t = threadIdx.x;
  const int colb = (t & 15) * 4;
  const int r0 = t >> 4;
  __shared__ f16 Lt[64 * 64];
  float* outb = out + (size_t)side * ((size_t)NB * 2 * NC * NHW) + (size_t)b * (2 * NC * NHW);
  f16* Xhb = Xh + (size_t)side * ((size_t)NB * NC * NHW) + (size_t)b * NC * NHW;
  f16* Xtb = Xt + (size_t)side * ((size_t)NB * NHW * NC) + (size_t)b * NHW * NC;
#pragma unroll
  for (int p = 0; p < 4; ++p) {
    int r = r0 + p * 16;
    size_t go = (size_t)(c0 + r) * NHW + hw0 + colb;
    float4 v = *(const float4*)&X[go];
    *(float4*)&outb[go] = v;
    f16x4 h; h[0] = (f16)v.x; h[1] = (f16)v.y; h[2] = (f16)v.z; h[3] = (f16)v.w;
    *(f16x4*)&Xhb[go] = h;
#pragma unroll
    for (int j = 0; j < 4; ++j) {
      int row = colb + j;
      int byte = row * 128 + ((r * 2) ^ ((((row >> 2) & 7)) << 4));
      *(f16*)((char*)Lt + byte) = h[j];
    }
  }
  __syncthreads();
#pragma unroll
  for (int p = 0; p < 2; ++p) {
    int idx = p * 256 + t;
    int row = idx >> 3, ch = idx & 7;
    int byte = row * 128 + (((ch ^ ((row >> 2) & 7))) << 4);
    f16x8 vv = *(const f16x8*)((char*)Lt + byte);
    *(f16x8*)&Xtb[(size_t)(hw0 + row) * NC + c0 + ch * 8] = vv;
  }
}

// ---- W stack to f16: Ws[512][2048] ----
__global__ __launch_bounds__(256) void k_w16(
    const float* __restrict__ wq, const float* __restrict__ wk, f16* __restrict__ Ws) {
  const int N4 = NHC * NC / 4;
  int idx = blockIdx.x * 256 + threadIdx.x;
  const float* src = (idx < N4) ? wq : wk;
  int e4 = (idx < N4) ? idx : idx - N4;
  float4 v = ((const float4*)src)[e4];
  f16x4 h; h[0] = (f16)v.x; h[1] = (f16)v.y; h[2] = (f16)v.z; h[3] = (f16)v.w;
  ((f16x4*)Ws)[idx] = h;
}

// ---- proj: Yt[i][512] = Ws x Xt + bias (128x128, BK=32, 2-phase dbuf) ----
__global__ __launch_bounds__(256) void k_proj(
    const f16* __restrict__ Ws, const f16* __restrict__ Xt,
    const float* __restrict__ bq, const float* __restrict__ bk,
    f16* __restrict__ Yt) {
  __shared__ f16 LA[2][128 * 32], LB[2][128 * 32];
  const int n0 = blockIdx.x * 128;
  const int m0 = blockIdx.y * 128;
  const int tid = threadIdx.x, wv = tid >> 6, ln = tid & 63;
  const int lr = ln & 15, lh = ln >> 4;
  const int wm = wv >> 1, wn = wv & 1;
  f32x4 acc[4][4];
#pragma unroll
  for (int mi = 0; mi < 4; ++mi)
#pragma unroll
    for (int ni = 0; ni < 4; ++ni)
#pragma unroll
      for (int q = 0; q < 4; ++q) acc[mi][ni][q] = 0.f;

  auto stage = [&](int bi, int ks) {
    int k0 = ks * 32;
#pragma unroll
    for (int rep = 0; rep < 2; ++rep) {
      int u = rep * 256 + wv * 64 + ln;
      int r = u >> 2, k8 = (u & 3) * 8;
      int ub8 = (rep * 256 + wv * 64) * 8;
      glds16(Ws + (size_t)(m0 + r) * NC + k0 + k8, &LA[bi][ub8]);
      glds16(Xt + (size_t)(n0 + r) * NC + k0 + k8, &LB[bi][ub8]);
    }
  };
  auto compute = [&](int bi) {
    f16x8 af[4], bf[4];
#pragma unroll
    for (int mi = 0; mi < 4; ++mi)
      af[mi] = *(const f16x8*)&LA[bi][(wm * 64 + mi * 16 + lr) * 32 + lh * 8];
#pragma unroll
    for (int ni = 0; ni < 4; ++ni)
      bf[ni] = *(const f16x8*)&LB[bi][(wn * 64 + ni * 16 + lr) * 32 + lh * 8];
#pragma unroll
    for (int mi = 0; mi < 4; ++mi)
#pragma unroll
      for (int ni = 0; ni < 4; ++ni)
        acc[mi][ni] = __builtin_amdgcn_mfma_f32_16x16x32_f16(af[mi], bf[ni], acc[mi][ni], 0, 0, 0);
  };

  stage(0, 0);
  __syncthreads();
  int cur = 0;
  for (int ks = 0; ks < 63; ++ks) {
    stage(cur ^ 1, ks + 1);
    compute(cur);
    __syncthreads();
    cur ^= 1;
  }
  compute(cur);

#pragma unroll
  for (int mi = 0; mi < 4; ++mi)
#pragma unroll
    for (int ni = 0; ni < 4; ++ni) {
      int ob = m0 + wm * 64 + mi * 16 + lh * 4;
      int i = n0 + wn * 64 + ni * 16 + lr;
      f16x4 hv;
#pragma unroll
      for (int q = 0; q < 4; ++q) {
        int o = ob + q;
        float bias = (o < NHC) ? bq[o] : bk[o - NHC];
        hv[q] = (f16)(acc[mi][ni][q] + bias);
      }
      *(f16x4*)&Yt[(size_t)i * 512 + ob] = hv;
    }
}

// ---- scores: S[b][i][j] = sum_hc Q[i,hc]*K[j,hc] (128x128, BK=32, 2-phase) ----
__global__ __launch_bounds__(256) void k_scores(
    const f16* __restrict__ Q, const f16* __restrict__ K, float* __restrict__ S) {
  __shared__ f16 LA[2][128 * 32], LB[2][128 * 32];
  const int b = blockIdx.z;
  const int i0 = blockIdx.x * 128, j0 = blockIdx.y * 128;
  const int tid = threadIdx.x, wv = tid >> 6, ln = tid & 63;
  const int lr = ln & 15, lh = ln >> 4;
  const int wm = wv >> 1, wn = wv & 1;
  const f16* Qb = Q + (size_t)b * NHW * 512;
  const f16* Kb = K + (size_t)b * NHW * 512;
  f32x4 acc[4][4];
#pragma unroll
  for (int mi = 0; mi < 4; ++mi)
#pragma unroll
    for (int ni = 0; ni < 4; ++ni)
#pragma unroll
      for (int q = 0; q < 4; ++q) acc[mi][ni][q] = 0.f;

  auto stage = [&](int bi, int ks) {
    int k0 = ks * 32;
#pragma unroll
    for (int rep = 0; rep < 2; ++rep) {
      int u = rep * 256 + wv * 64 + ln;
      int r = u >> 2, k8 = (u & 3) * 8;
      int ub8 = (rep * 256 + wv * 64) * 8;
      glds16(Qb + (size_t)(i0 + r) * 512 + k0 + k8, &LA[bi][ub8]);
      glds16(Kb + (size_t)(j0 + r) * 512 + k0 + k8, &LB[bi][ub8]);
    }
  };
  auto compute = [&](int bi) {
    f16x8 af[4], bf[4];
#pragma unroll
    for (int mi = 0; mi < 4; ++mi)
      af[mi] = *(const f16x8*)&LA[bi][(wm * 64 + mi * 16 + lr) * 32 + lh * 8];
#pragma unroll
    for (int ni = 0; ni < 4; ++ni)
      bf[ni] = *(const f16x8*)&LB[bi][(wn * 64 + ni * 16 + lr) * 32 + lh * 8];
#pragma unroll
    for (int mi = 0; mi < 4; ++mi)
#pragma unroll
      for (int ni = 0; ni < 4; ++ni)
        acc[mi][ni] = __builtin_amdgcn_mfma_f32_16x16x32_f16(af[mi], bf[ni], acc[mi][ni], 0, 0, 0);
  };

  stage(0, 0);
  __syncthreads();
  int cur = 0;
  for (int ks = 0; ks < 7; ++ks) {
    stage(cur ^ 1, ks + 1);
    compute(cur);
    __syncthreads();
    cur ^= 1;
  }
  compute(cur);

  float* Sb = S + (size_t)b * NHW * NHW;
#pragma unroll
  for (int mi = 0; mi < 4; ++mi)
#pragma unroll
    for (int ni = 0; ni < 4; ++ni) {
      int i = i0 + wm * 64 + mi * 16 + lh * 4;
      int j = j0 + wn * 64 + ni * 16 + lr;
#pragma unroll
      for (int q = 0; q < 4; ++q)
        Sb[(size_t)(i + q) * NHW + j] = acc[mi][ni][q];
    }
}

// ---- row softmax, f32 -> f16 attn written in-place over row start ----
__global__ __launch_bounds__(256) void k_softmax(float* __restrict__ S) {
  const int row = blockIdx.x;
  float* rp = S + (size_t)row * NHW;
  const int t = threadIdx.x;
  float v[9];
  float m = -3.4e38f;
#pragma unroll
  for (int k = 0; k < 9; ++k) { v[k] = rp[t + 256 * k]; m = fmaxf(m, v[k]); }
#pragma unroll
  for (int off = 32; off > 0; off >>= 1) m = fmaxf(m, __shfl_xor(m, off));
  __shared__ float red[4];
  __shared__ float red2[4];
  const int wv = t >> 6, ln = t & 63;
  if (ln == 0) red[wv] = m;
  __syncthreads();
  m = fmaxf(fmaxf(red[0], red[1]), fmaxf(red[2], red[3]));
  float s = 0.f;
#pragma unroll
  for (int k = 0; k < 9; ++k) { v[k] = expf(v[k] - m); s += v[k]; }
#pragma unroll
  for (int off = 32; off > 0; off >>= 1) s += __shfl_xor(s, off);
  if (ln == 0) red2[wv] = s;
  __syncthreads();
  float inv = 1.0f / (red2[0] + red2[1] + red2[2] + red2[3]);
  f16* op = (f16*)rp;
#pragma unroll
  for (int k = 0; k < 9; ++k) op[t + 256 * k] = (f16)(v[k] * inv);
}

// ---- PV, deep-pipelined: out[b][2048+c][i] = sum_j V[b][c][j]*attn[b][i][j] ----
// BM=256 (c), BN=128 (i), BK=64 (j). 512 threads = 8 waves (4M x 2N), 64x64/wave.
// Ring-3 LDS K-tiles; stage tile t+2 while computing t; vmcnt(6) per tile.
__global__ __launch_bounds__(512, 2) void k_pv8(
    const f16* __restrict__ V0, const f16* __restrict__ V1,
    const float* __restrict__ S0, const float* __restrict__ S1,
    float* __restrict__ out, int ndirs, long long ob0, long long ob1) {
  extern __shared__ __align__(16) f16 SH[];
  f16* LA = SH;               // 3 slots x 16384 f16 (32 KB each): [256][64]
  f16* LB = SH + 3 * 16384;   // 3 slots x  8192 f16 (16 KB each): [128][64]

  const int nwg = ndirs * 576;
  const int bid = blockIdx.x;
  const int wg = (bid & 7) * (nwg >> 3) + (bid >> 3);  // XCD swizzle (nwg%8==0)
  const int n = wg % 18;
  const int r1 = wg / 18;
  const int m = r1 & 7;
  const int r2 = r1 >> 3;
  const int b = r2 & 3;
  const int dir = r2 >> 2;

  const f16* Vb = (dir ? V1 : V0) + (size_t)b * NC * NHW;
  const char* Sb = (const char*)(dir ? S1 : S0) + (size_t)b * NHW * NHW * 4;
  const long long obase = dir ? ob1 : ob0;
  const int c0 = m * 256, i0 = n * 128;
  const int tid = threadIdx.x, wv = tid >> 6, ln = tid & 63;
  const int lr = ln & 15, lg = ln >> 4;
  const int wm = wv >> 1, wn = wv & 1;

  // staging thread map: chunk = 64 rows x 128 B; thread covers (fr, (tid&7)*16)
  const int fr = tid >> 3;
  const int scolb = ((tid & 7) * 16) ^ ((fr & 7) << 4);  // pre-swizzled source col
  const f16* aSrc = Vb + (size_t)(c0 + fr) * NHW + (scolb >> 1);
  const char* bSrc = Sb + (size_t)(i0 + fr) * 9216 + scolb;
  const int ldsW = wv * 512;  // wave-uniform chunk share (f16 elems)

  auto stA = [&](int s, int t2, int r) {
    glds16(aSrc + (size_t)r * 64 * NHW + t2 * 64, LA + s * 16384 + r * 4096 + ldsW);
  };
  auto stB = [&](int s, int t2, int r) {
    glds16(bSrc + (size_t)r * 64 * 9216 + t2 * 128, LB + s * 8192 + r * 4096 + ldsW);
  };
  auto rdA = [&](int s, int mi, int ks) -> f16x8 {
    int row = wm * 64 + mi * 16 + lr;
    int colb = (ks * 64 + lg * 16) ^ ((row & 7) << 4);
    return *(const f16x8*)((const char*)(LA + s * 16384) + row * 128 + colb);
  };
  auto rdB = [&](int s, int ni, int ks) -> f16x8 {
    int row = wn * 64 + ni * 16 + lr;
    int colb = (ks * 64 + lg * 16) ^ ((row & 7) << 4);
    return *(const f16x8*)((const char*)(LB + s * 8192) + row * 128 + colb);
  };

  f32x4 acc[4][4];
#pragma unroll
  for (int mi = 0; mi < 4; ++mi)
#pragma unroll
    for (int ni = 0; ni < 4; ++ni)
#pragma unroll
      for (int q = 0; q < 4; ++q) acc[mi][ni][q] = 0.f;

  // prologue: stage tiles 0 and 1 (6 chunks each)
#pragma unroll
  for (int r = 0; r < 4; ++r) stA(0, 0, r);
  stB(0, 0, 0); stB(0, 0, 1);
#pragma unroll
  for (int r = 0; r < 4; ++r) stA(1, 1, r);
  stB(1, 1, 0); stB(1, 1, 1);
  asm volatile("s_waitcnt vmcnt(6)" ::: "memory");  // tile 0 landed
  asm volatile("s_barrier" ::: "memory");

  int s = 0;
  for (int t = 0; t < NT; ++t) {
    int s2 = s + 2; if (s2 >= 3) s2 -= 3;
    const bool st = (t + 2 < NT);
    // ---------- phase 1: B frags + A(mi 0-1); stage A r0-2 of t+2 ----------
    f16x8 bf[4][2], af[2][2];
#pragma unroll
    for (int ni = 0; ni < 4; ++ni) { bf[ni][0] = rdB(s, ni, 0); bf[ni][1] = rdB(s, ni, 1); }
#pragma unroll
    for (int mi = 0; mi < 2; ++mi) { af[mi][0] = rdA(s, mi, 0); af[mi][1] = rdA(s, mi, 1); }
    if (st) { stA(s2, t + 2, 0); stA(s2, t + 2, 1); stA(s2, t + 2, 2); }
    asm volatile("s_barrier" ::: "memory");
    __builtin_amdgcn_s_setprio(1);
#pragma unroll
    for (int ks = 0; ks < 2; ++ks)
#pragma unroll
      for (int mi = 0; mi < 2; ++mi)
#pragma unroll
        for (int ni = 0; ni < 4; ++ni)
          acc[mi][ni] = __builtin_amdgcn_mfma_f32_16x16x32_f16(af[mi][ks], bf[ni][ks], acc[mi][ni], 0, 0, 0);
    __builtin_amdgcn_s_setprio(0);
    asm volatile("s_barrier" ::: "memory");
    // ---------- phase 2: A(mi 2-3); stage A r3 + B r0-1 of t+2; vmcnt ----------
    f16x8 a2[2][2];
#pragma unroll
    for (int mi = 0; mi < 2; ++mi) { a2[mi][0] = rdA(s, 2 + mi, 0); a2[mi][1] = rdA(s, 2 + mi, 1); }
    if (st) { stA(s2, t + 2, 3); stB(s2, t + 2, 0); stB(s2, t + 2, 1); }
    if (t < NT - 2) { asm volatile("s_waitcnt vmcnt(6)" ::: "memory"); }
    else            { asm volatile("s_waitcnt vmcnt(0)" ::: "memory"); }
    asm volatile("s_barrier" ::: "memory");
    __builtin_amdgcn_s_setprio(1);
#pragma unroll
    for (int ks = 0; ks < 2; ++ks)
#pragma unroll
      for (int mi = 0; mi < 2; ++mi)
#pragma unroll
        for (int ni = 0; ni < 4; ++ni)
          acc[2 + mi][ni] = __builtin_amdgcn_mfma_f32_16x16x32_f16(a2[mi][ks], bf[ni][ks], acc[2 + mi][ni], 0, 0, 0);
    __builtin_amdgcn_s_setprio(0);
    asm volatile("s_barrier" ::: "memory");
    s += 1; if (s == 3) s = 0;
  }

  float* ob = out + obase + (size_t)b * (2 * NC * NHW);
#pragma unroll
  for (int mi = 0; mi < 4; ++mi)
#pragma unroll
    for (int ni = 0; ni < 4; ++ni) {
      int c = c0 + wm * 64 + mi * 16 + lg * 4;
      int i = i0 + wn * 64 + ni * 16 + lr;
#pragma unroll
      for (int q = 0; q < 4; ++q)
        ob[(size_t)(NC + c + q) * NHW + i] = acc[mi][ni][q];
    }
}

extern "C" void kernel_launch(void* const* d_in, const int* in_sizes, int n_in,
                              void* d_out, int out_size, void* d_ws, size_t ws_size,
                              hipStream_t stream) {
  const float* xl = (const float*)d_in[0];
  const float* xr = (const float*)d_in[1];
  const float* wq = (const float*)d_in[2];
  const float* bq = (const float*)d_in[3];
  const float* wk = (const float*)d_in[4];
  const float* bk = (const float*)d_in[5];
  float* out = (float*)d_out;
  char* ws = (char*)d_ws;

  const size_t XH_BYTES = (size_t)2 * NB * NC * NHW * 2;   // 75,497,472
  const size_t WS_BYTES = (size_t)512 * NC * 2;            //  2,097,152
  const size_t YT_BYTES = (size_t)2 * NB * NHW * 512 * 2;  // 18,874,368
  const size_t S_BYTES  = (size_t)NB * NHW * NHW * 4;      // 84,934,656

  f16* Xh = (f16*)ws;
  f16* Ws_ = (f16*)(ws + XH_BYTES);
  f16* Yt = (f16*)(ws + XH_BYTES + WS_BYTES);
  char* rest = ws + XH_BYTES + WS_BYTES + YT_BYTES;

  const size_t xh_side = (size_t)NB * NC * NHW;
  const size_t xt_side = (size_t)NB * NHW * NC;
  const size_t yt_side = (size_t)NB * NHW * 512;
  const long long obA = (long long)NB * 2 * NC * NHW;  // right_attended weighted half
  const long long obB = 0;                             // left_attended weighted half

  const bool merged = ws_size >= XH_BYTES + WS_BYTES + YT_BYTES + 2 * S_BYTES;

  if (merged) {
    float* S0 = (float*)rest;
    char* rest2 = rest + S_BYTES;
    f16* Xt = (f16*)rest2;   // aliases S1 (consumed by proj before scores-B)
    float* S1 = (float*)rest2;

    k_prep<<<dim3(36, 32, 8), dim3(256), 0, stream>>>(xl, xr, out, Xh, Xt);
    k_w16<<<dim3(1024), dim3(256), 0, stream>>>(wq, wk, Ws_);
    k_proj<<<dim3(72, 4), dim3(256), 0, stream>>>(Ws_, Xt, bq, bk, Yt);
    k_proj<<<dim3(72, 4), dim3(256), 0, stream>>>(Ws_, Xt + xt_side, bq, bk, Yt + yt_side);

    k_scores<<<dim3(18, 18, NB), dim3(256), 0, stream>>>(Yt, Yt + yt_side + NHC, S0);
    k_scores<<<dim3(18, 18, NB), dim3(256), 0, stream>>>(Yt + yt_side, Yt + NHC, S1);
    k_softmax<<<dim3(NB * NHW), dim3(256), 0, stream>>>(S0);
    k_softmax<<<dim3(NB * NHW), dim3(256), 0, stream>>>(S1);
    k_pv8<<<dim3(1152), dim3(512), 147456, stream>>>(
        Xh + xh_side, Xh, S0, S1, out, 2, obA, obB);
  } else {
    f16* Xt = (f16*)rest;   // aliases S
    float* S = (float*)rest;

    k_prep<<<dim3(36, 32, 8), dim3(256), 0, stream>>>(xl, xr, out, Xh, Xt);
    k_w16<<<dim3(1024), dim3(256), 0, stream>>>(wq, wk, Ws_);
    k_proj<<<dim3(72, 4), dim3(256), 0, stream>>>(Ws_, Xt, bq, bk, Yt);
    k_proj<<<dim3(72, 4), dim3(256), 0, stream>>>(Ws_, Xt + xt_side, bq, bk, Yt + yt_side);

    k_scores<<<dim3(18, 18, NB), dim3(256), 0, stream>>>(Yt, Yt + yt_side + NHC, S);
    k_softmax<<<dim3(NB * NHW), dim3(256), 0, stream>>>(S);
    k_pv8<<<dim3(576), dim3(512), 147456, stream>>>(
        Xh + xh_side, Xh + xh_side, S, S, out, 1, obA, obA);

    k_scores<<<dim3(18, 18, NB), dim3(256), 0, stream>>>(Yt + yt_side, Yt + NHC, S);
    k_softmax<<<dim3(NB * NHW), dim3(256), 0, stream>>>(S);
    k_pv8<<<dim3(576), dim3(512), 147456, stream>>>(
        Xh, Xh, S, S, out, 1, obB, obB);
  }
}